// Round 6
// baseline (346.125 us; speedup 1.0000x reference)
//
#include <hip/hip_runtime.h>
#include <hip/hip_bf16.h>

// GConvGRU (ChebConv K=2), fp32 in/out; bf16 MFMA GEMM; fp8 gather path.
// Zin row K-layout: [x | hx | px | ph] (512 bf16 = 1 KB/node).
// xf8 QUARTER-MAJOR: xf8q[p][node][64B], p in 0..3 -> each agg pass's
//   gather slice is 3.2 MB < 4 MB per-XCD L2 (L2-resident, no capacity miss).
// agg: grid (N/4, 4); pass p = blockIdx.y (x-fastest dispatch => phase order).
//   Wave per node: 16 edges/iter x 4 lanes x 16B, 1-deep prefetch,
//   4-step shuffle reduce, lanes 0-3 write the 128B quarter of px/ph.
// GEMM: 128x128 tile, fused gate epilogue, dbuf LDS + counted vmcnt(4).
// CSR build = counting sort with BLOCK-PRIVATE scatter windows.

typedef unsigned short u16;
typedef unsigned int u32;
typedef __attribute__((ext_vector_type(8))) __bf16 bf16x8;
typedef __attribute__((ext_vector_type(4))) float f32x4;
typedef __attribute__((ext_vector_type(2))) float f32x2;
typedef __attribute__((ext_vector_type(4))) int int4v;

#define F_IN 128
#define HID 128
#define NPS 512           // nodes per segment (power of 2: r = d >> 9)
#define NPS_SHIFT 9

__device__ __forceinline__ u16 f2bf(float f) {
    u32 u;
    __builtin_memcpy(&u, &f, 4);
    u = (u + 0x7fffu + ((u >> 16) & 1u)) >> 16;
    return (u16)u;
}
__device__ __forceinline__ u32 packbf(float a, float b) {
    return ((u32)f2bf(b) << 16) | (u32)f2bf(a);
}
__device__ __forceinline__ float sigmoidf_(float x) {
    return 1.0f / (1.0f + __expf(-x));
}

__device__ __forceinline__ void async_copy16(void* lds, const void* gptr) {
    __builtin_amdgcn_global_load_lds(
        (__attribute__((address_space(1))) void*)gptr,
        (__attribute__((address_space(3))) void*)lds,
        16, 0, 0);
}

// ------------- 1. bucket: partition COO into NSEG segments of NPS nodes -------------
__global__ __launch_bounds__(256) void bucket_kernel(const int* __restrict__ src,
                                                     const int* __restrict__ dst, int E,
                                                     int* __restrict__ segCount,
                                                     int2* __restrict__ bedges,
                                                     int segCap, int edgesPerChunk,
                                                     int NSEG) {
    __shared__ int cnt[128], base[128], pos[128];
    for (int i = threadIdx.x; i < NSEG; i += 256) cnt[i] = 0;
    __syncthreads();
    int beg = blockIdx.x * edgesPerChunk;
    int end = beg + edgesPerChunk;
    if (end > E) end = E;
    // pass 1: per-segment counts
    for (int i = beg + (int)threadIdx.x * 4; i < end; i += 256 * 4) {
        if (i + 4 <= end) {
            int4v d4 = *(const int4v*)(dst + i);
#pragma unroll
            for (int j = 0; j < 4; ++j) atomicAdd(&cnt[(unsigned)d4[j] >> NPS_SHIFT], 1);
        } else {
            for (int j = i; j < end; ++j) atomicAdd(&cnt[(unsigned)dst[j] >> NPS_SHIFT], 1);
        }
    }
    __syncthreads();
    for (int i = threadIdx.x; i < NSEG; i += 256) {
        base[i] = atomicAdd(&segCount[i], cnt[i]);
        pos[i] = 0;
    }
    __syncthreads();
    // pass 2: emit (chunk is cache-hot from pass 1)
    for (int i = beg + (int)threadIdx.x * 4; i < end; i += 256 * 4) {
        if (i + 4 <= end) {
            int4v d4 = *(const int4v*)(dst + i);
            int4v s4 = *(const int4v*)(src + i);
#pragma unroll
            for (int j = 0; j < 4; ++j) {
                int d = d4[j];
                unsigned r = (unsigned)d >> NPS_SHIFT;
                int p = atomicAdd(&pos[r], 1);
                int o = base[r] + p;
                if (o < segCap) bedges[(size_t)r * segCap + o] = make_int2(d, s4[j]);
            }
        } else {
            for (int j = i; j < end; ++j) {
                int d = dst[j];
                unsigned r = (unsigned)d >> NPS_SHIFT;
                int p = atomicAdd(&pos[r], 1);
                int o = base[r] + p;
                if (o < segCap) bedges[(size_t)r * segCap + o] = make_int2(d, src[j]);
            }
        }
    }
}

// ------------- 2. fused per-segment CSR: hist + scan + row_ptr + norm + fill -------------
__global__ __launch_bounds__(1024) void csr_kernel(const int2* __restrict__ bedges,
                                                   const int* __restrict__ segCount,
                                                   int* __restrict__ row_ptr,
                                                   float* __restrict__ norm,
                                                   int* __restrict__ esrc,
                                                   int segCap, int N, int E, int NSEG) {
    __shared__ int hist[NPS];
    __shared__ int sseg[128];
    __shared__ int segBaseSh;
    int seg = blockIdx.x;
    int tid = threadIdx.x;
    int lo = seg << NPS_SHIFT;
    int npr = N - lo;
    if (npr > NPS) npr = NPS;

    // mini-scan of segCount[0..NSEG) for segBase
    if (tid < 128) sseg[tid] = (tid < NSEG) ? segCount[tid] : 0;
    __syncthreads();
    for (int off = 1; off < 128; off <<= 1) {
        int v = 0;
        if (tid < 128 && tid >= off) v = sseg[tid - off];
        __syncthreads();
        if (tid < 128) sseg[tid] += v;
        __syncthreads();
    }
    if (tid == 0) segBaseSh = (seg == 0) ? 0 : sseg[seg - 1];
    if (tid < NPS) hist[tid] = 0;
    __syncthreads();

    int cnt = segCount[seg];
    if (cnt > segCap) cnt = segCap;
    const int2* segp = bedges + (size_t)seg * segCap;

    // pass 1: histogram dst
    for (int i = tid; i < cnt; i += 1024) atomicAdd(&hist[segp[i].x - lo], 1);
    __syncthreads();
    int myCount = (tid < NPS) ? hist[tid] : 0;
    __syncthreads();
    // inclusive scan of hist
    for (int off = 1; off < NPS; off <<= 1) {
        int v = 0;
        if (tid < NPS && tid >= off) v = hist[tid - off];
        __syncthreads();
        if (tid < NPS) hist[tid] += v;
        __syncthreads();
    }
    int segBase = segBaseSh;
    if (tid < npr) {
        int excl = hist[tid] - myCount;
        row_ptr[lo + tid] = segBase + excl;
        norm[lo + tid] = rsqrtf((float)(myCount > 1 ? myCount : 1));
    }
    __syncthreads();
    if (tid < NPS) hist[tid] = segBase + hist[tid] - myCount;  // global cursors
    __syncthreads();
    // pass 2: fill (private window)
    for (int i = tid; i < cnt; i += 1024) {
        int2 e = segp[i];
        int slot = atomicAdd(&hist[e.x - lo], 1);
        esrc[slot] = e.y;
    }
    if (seg == NSEG - 1 && tid == 0) row_ptr[N] = E;
}

// ------------- 3. convert: x,hx -> Zin bf16 slots + prescaled fp8 (quarter-major) -------
__global__ void convert_kernel(const float* __restrict__ x, const float* __restrict__ hx,
                               const float* __restrict__ norm,
                               u32* __restrict__ zin, u32* __restrict__ xf8, int N) {
    int t = blockIdx.x * blockDim.x + threadIdx.x;
    if (t >= N * 64) return;
    int n = t >> 6, c4 = t & 63;
    float4 v;
    int zbase;
    if (c4 < 32) {
        v = ((const float4*)x)[n * 32 + c4];
        zbase = n * 256 + 2 * c4;
    } else {
        v = ((const float4*)hx)[n * 32 + (c4 - 32)];
        zbase = n * 256 + 64 + 2 * (c4 - 32);
    }
    zin[zbase] = packbf(v.x, v.y);
    zin[zbase + 1] = packbf(v.z, v.w);
    float ns = norm[n];
    u32 o = 0;
    o = (u32)__builtin_amdgcn_cvt_pk_fp8_f32(v.x * ns, v.y * ns, (int)o, false);
    o = (u32)__builtin_amdgcn_cvt_pk_fp8_f32(v.z * ns, v.w * ns, (int)o, true);
    // quarter-major: slice p holds concat-features [p*64, p*64+64) for all nodes
    int p = c4 >> 4;
    xf8[(size_t)p * N * 16 + n * 16 + (c4 & 15)] = o;
}

// ------------- 4. weight prepack (fp32 -> bf16, interleaved cols) + bias pack -------------
// Col layout: c' = (f>>4)*64 + part*16 + (f&15), part in {r,u,cx,ch}.
__global__ void prep_kernel(const float* __restrict__ Wrx, const float* __restrict__ Wrh,
                            const float* __restrict__ Wux, const float* __restrict__ Wuh,
                            const float* __restrict__ Wcx, const float* __restrict__ Wch,
                            const float* __restrict__ brx, const float* __restrict__ brh,
                            const float* __restrict__ bux, const float* __restrict__ buh,
                            const float* __restrict__ bcx, const float* __restrict__ bch,
                            u16* __restrict__ WT, float* __restrict__ bias) {
    int t = blockIdx.x * blockDim.x + threadIdx.x;  // [0, 512*512)
    int cp = t >> 9, k = t & 511;
    int fc = cp >> 6, p = (cp >> 4) & 3, cf = cp & 15;
    int f = fc * 16 + cf;                 // feature 0..127
    int kpart = k >> 7;
    int kf = k & 127;
    int t01 = (kpart & 2) ? 1 : 0;
    bool isX = !(kpart & 1);
    int wi = t01 * (128 * 128) + kf * 128 + f;
    float val = 0.0f;
    if (p == 0) val = isX ? Wrx[wi] : Wrh[wi];
    else if (p == 1) val = isX ? Wux[wi] : Wuh[wi];
    else if (p == 2) { if (isX) val = Wcx[wi]; }
    else { if (!isX) val = Wch[wi]; }
    WT[t] = f2bf(val);
    if (t < 512) {
        int bp = (t >> 4) & 3;
        int bf_ = (t >> 6) * 16 + (t & 15);
        float b = 0.0f;
        if (bp == 0) b = brx[bf_] + brh[bf_];
        else if (bp == 1) b = bux[bf_] + buh[bf_];
        else if (bp == 2) b = bcx[bf_];
        else b = bch[bf_];
        bias[t] = b;
    }
}

// ------------- 5. agg: wave-per-node, quarter-pass (L2-resident slice) -------------
__device__ __forceinline__ void accum4(f32x2* acc, uint4 v) {
#pragma unroll
    for (int i = 0; i < 4; ++i) {
        u32 w = (i == 0) ? v.x : (i == 1) ? v.y : (i == 2) ? v.z : v.w;
        acc[2 * i] += (f32x2)__builtin_amdgcn_cvt_pk_f32_fp8((int)w, false);
        acc[2 * i + 1] += (f32x2)__builtin_amdgcn_cvt_pk_f32_fp8((int)w, true);
    }
}

__global__ __launch_bounds__(256) void agg_kernel(const int* __restrict__ row_ptr,
                                                  const int* __restrict__ esrc,
                                                  const float* __restrict__ norm,
                                                  const u32* __restrict__ xf8,
                                                  u32* __restrict__ zin, int N) {
    int node = blockIdx.x * 4 + (threadIdx.x >> 6);
    int lane = threadIdx.x & 63;
    if (node >= N) return;
    int p = blockIdx.y;            // feature-quarter pass (x-fastest dispatch)
    int e16 = lane >> 2;           // edge slot 0..15
    int li4 = lane & 3;            // uint4 slot within the 64B quarter row
    int beg = row_ptr[node], end = row_ptr[node + 1];
    const uint4* z4 = (const uint4*)xf8 + (size_t)p * N * 4;
    f32x2 acc[8];
#pragma unroll
    for (int i = 0; i < 8; ++i) acc[i] = (f32x2){0.f, 0.f};

    // 16 edges/iter, 1-deep prefetch
    int e = beg + e16;
    bool have = e < end;
    uint4 v = {0, 0, 0, 0};
    if (have) {
        int s = esrc[e];
        v = z4[(size_t)s * 4 + li4];
    }
    while (have) {
        int en = e + 16;
        bool more = en < end;
        uint4 vn = {0, 0, 0, 0};
        if (more) {
            int sn = esrc[en];
            vn = z4[(size_t)sn * 4 + li4];   // next iter's gather in flight
        }
        accum4(acc, v);
        e = en;
        v = vn;
        have = more;
    }
    // butterfly reduce across the 16 edge-slots (stride-4 lanes)
#pragma unroll
    for (int i = 0; i < 8; ++i) {
        acc[i].x += __shfl_xor(acc[i].x, 4);
        acc[i].y += __shfl_xor(acc[i].y, 4);
        acc[i].x += __shfl_xor(acc[i].x, 8);
        acc[i].y += __shfl_xor(acc[i].y, 8);
        acc[i].x += __shfl_xor(acc[i].x, 16);
        acc[i].y += __shfl_xor(acc[i].y, 16);
        acc[i].x += __shfl_xor(acc[i].x, 32);
        acc[i].y += __shfl_xor(acc[i].y, 32);
    }
    if (lane < 4) {
        float nn = -norm[node];
        uint4 o0, o1;
        o0.x = packbf(acc[0].x * nn, acc[0].y * nn);
        o0.y = packbf(acc[1].x * nn, acc[1].y * nn);
        o0.z = packbf(acc[2].x * nn, acc[2].y * nn);
        o0.w = packbf(acc[3].x * nn, acc[3].y * nn);
        o1.x = packbf(acc[4].x * nn, acc[4].y * nn);
        o1.y = packbf(acc[5].x * nn, acc[5].y * nn);
        o1.z = packbf(acc[6].x * nn, acc[6].y * nn);
        o1.w = packbf(acc[7].x * nn, acc[7].y * nn);
        // quarter p covers concat cols [p*64, p*64+64): p<2 -> px, else ph
        int zq = (p < 2) ? (128 + p * 32) : (192 + (p - 2) * 32);
        uint4* d4 = (uint4*)(zin + (size_t)node * 256 + zq) + lane * 2;
        d4[0] = o0;
        d4[1] = o1;
    }
}

// ------------- 6. MFMA GEMM (128x128, dbuf + counted vmcnt) + fused epilogue -------------
// Per k-tile per wave: 4 global_load_lds. Loop: STAGE(next) -> vmcnt(4)
// (waits CURRENT tile's loads only; next stays in flight) -> barrier ->
// ds_read+MFMA -> lgkmcnt(0) -> barrier. Never vmcnt(0) until last tile.
__global__ __launch_bounds__(256) void gemm_fused_kernel(
        const u16* __restrict__ A, const u16* __restrict__ B,
        const float* __restrict__ bias, const float* __restrict__ hx,
        float* __restrict__ out, int N) {
    __shared__ __align__(16) __bf16 As[2][128 * 32];
    __shared__ __align__(16) __bf16 Bs[2][128 * 32];
    int tid = threadIdx.x;
    int wave = tid >> 6, lane = tid & 63;

    // bijective XCD swizzle (total = gridDim.x, not necessarily %8==0)
    int total = gridDim.x;
    int bid = blockIdx.x;
    int q = total >> 3, r = total & 7;
    int xcd = bid & 7, idx = bid >> 3;
    int wg = (xcd < r ? xcd * (q + 1) : r * (q + 1) + (xcd - r) * q) + idx;
    int m0 = (wg >> 2) * 128;
    int n0 = (wg & 3) * 128;

    int wm = wave & 1, wn = wave >> 1;
    int quad = lane >> 4, l15 = lane & 15;

    // per-wave staging geometry (2 chunks/wave, each 512 bf16 = 16 rows x 32)
    int chunk0 = wave * 2;
    int fl0 = chunk0 * 512 + lane * 8;
    int row0 = fl0 >> 5, col0 = fl0 & 31;
    int fl1 = (chunk0 + 1) * 512 + lane * 8;
    int row1 = fl1 >> 5, col1 = fl1 & 31;
    const u16* Arow0 = A + (size_t)(m0 + row0) * 512 + col0;
    const u16* Arow1 = A + (size_t)(m0 + row1) * 512 + col1;
    const u16* Brow0 = B + (size_t)(n0 + row0) * 512 + col0;
    const u16* Brow1 = B + (size_t)(n0 + row1) * 512 + col1;

    f32x4 acc[4][4];
#pragma unroll
    for (int mi = 0; mi < 4; ++mi)
#pragma unroll
        for (int ni = 0; ni < 4; ++ni) acc[mi][ni] = (f32x4){0.f, 0.f, 0.f, 0.f};

    // prologue: stage tile 0 into buf 0 (4 loads/wave in flight)
    async_copy16(&As[0][fl0], Arow0);
    async_copy16(&As[0][fl1], Arow1);
    async_copy16(&Bs[0][fl0], Brow0);
    async_copy16(&Bs[0][fl1], Brow1);

    int cur = 0;
    for (int t = 0; t < 16; ++t) {
        if (t < 15) {
            int k1 = (t + 1) * 32;
            async_copy16(&As[cur ^ 1][fl0], Arow0 + k1);
            async_copy16(&As[cur ^ 1][fl1], Arow1 + k1);
            async_copy16(&Bs[cur ^ 1][fl0], Brow0 + k1);
            async_copy16(&Bs[cur ^ 1][fl1], Brow1 + k1);
            // wait for tile t's 4 loads; tile t+1's 4 remain in flight
            asm volatile("s_waitcnt vmcnt(4)" ::: "memory");
        } else {
            asm volatile("s_waitcnt vmcnt(0)" ::: "memory");
        }
        __builtin_amdgcn_s_barrier();

        bf16x8 af[4], bfr[4];
#pragma unroll
        for (int mi = 0; mi < 4; ++mi)
            af[mi] = *(const bf16x8*)&As[cur][(wm * 64 + mi * 16 + l15) * 32 + quad * 8];
#pragma unroll
        for (int ni = 0; ni < 4; ++ni)
            bfr[ni] = *(const bf16x8*)&Bs[cur][(wn * 64 + ni * 16 + l15) * 32 + quad * 8];
#pragma unroll
        for (int mi = 0; mi < 4; ++mi)
#pragma unroll
            for (int ni = 0; ni < 4; ++ni)
                acc[mi][ni] = __builtin_amdgcn_mfma_f32_16x16x32_bf16(af[mi], bfr[ni],
                                                                      acc[mi][ni], 0, 0, 0);
        // this wave's ds_reads are consumed; make it explicit, then fence the
        // buffer swap so no wave's next STAGE overwrites a buffer still being read
        asm volatile("s_waitcnt lgkmcnt(0)" ::: "memory");
        __builtin_amdgcn_s_barrier();
        cur ^= 1;
    }

    // fused epilogue: part = ni, feature f = ((n0>>6)+wn)*16 + l15
    int f = ((n0 >> 6) + wn) * 16 + l15;
    int cbase = ((n0 >> 6) + wn) * 64 + l15;
    float bR = bias[cbase + 0];
    float bU = bias[cbase + 16];
    float bX = bias[cbase + 32];
    float bH = bias[cbase + 48];
#pragma unroll
    for (int mi = 0; mi < 4; ++mi) {
        f32x4 aR = acc[mi][0];
        f32x4 aU = acc[mi][1];
        f32x4 aX = acc[mi][2];
        f32x4 aH = acc[mi][3];
#pragma unroll
        for (int r2 = 0; r2 < 4; ++r2) {
            int row = m0 + wm * 64 + mi * 16 + quad * 4 + r2;
            if (row < N) {
                float h = hx[(size_t)row * 128 + f];
                float rr = sigmoidf_(aR[r2] + bR);
                float uu = sigmoidf_(aU[r2] + bU);
                float cc = sigmoidf_((aX[r2] + bX) + (aH[r2] + bH) * rr);
                out[(size_t)row * 128 + f] = uu * h + (1.0f - uu) * cc;
            }
        }
    }
}

extern "C" void kernel_launch(void* const* d_in, const int* in_sizes, int n_in,
                              void* d_out, int out_size, void* d_ws, size_t ws_size,
                              hipStream_t stream) {
    const int* ei = (const int*)d_in[0];
    int E = in_sizes[0] / 2;
    const float* x = (const float*)d_in[1];
    const float* hx = (const float*)d_in[2];
    int N = in_sizes[1] / F_IN;
    const float* Wrx = (const float*)d_in[3];
    const float* brx = (const float*)d_in[4];
    const float* Wrh = (const float*)d_in[5];
    const float* brh = (const float*)d_in[6];
    const float* Wux = (const float*)d_in[7];
    const float* bux = (const float*)d_in[8];
    const float* Wuh = (const float*)d_in[9];
    const float* buh = (const float*)d_in[10];
    const float* Wcx = (const float*)d_in[11];
    const float* bcx = (const float*)d_in[12];
    const float* Wch = (const float*)d_in[13];
    const float* bch = (const float*)d_in[14];

    int Mpad = ((N + 127) / 128) * 128;
    int NSEG = (N + NPS - 1) / NPS;          // 98 for N=50000
    int segCap = E / NSEG + 2048;            // ~16σ slack over mean

    char* ws = (char*)d_ws;
    size_t off = 0;
    auto alloc = [&](size_t bytes) {
        size_t o = off;
        off = (off + bytes + 255) & ~(size_t)255;
        return o;
    };
    int* segCount = (int*)(ws + alloc(512));
    int* row_ptr = (int*)(ws + alloc((size_t)(N + 1) * 4));
    float* norm = (float*)(ws + alloc((size_t)N * 4));
    int* esrc = (int*)(ws + alloc((size_t)E * 4));
    int2* bedges = (int2*)(ws + alloc((size_t)NSEG * segCap * 8));
    u16* WT = (u16*)(ws + alloc((size_t)512 * 512 * 2));
    float* bias = (float*)(ws + alloc((size_t)512 * 4));
    u32* xf8 = (u32*)(ws + alloc((size_t)N * 64 * 4));
    u16* Zin = (u16*)(ws + alloc((size_t)Mpad * 512 * 2));
    (void)ws_size;

    hipMemsetAsync(segCount, 0, 512, stream);
    {
        const int bChunks = 256;
        int epc = (((E + bChunks - 1) / bChunks) + 3) & ~3;
        bucket_kernel<<<bChunks, 256, 0, stream>>>(ei, ei + E, E, segCount, bedges,
                                                   segCap, epc, NSEG);
    }
    csr_kernel<<<NSEG, 1024, 0, stream>>>(bedges, segCount, row_ptr, norm, esrc,
                                          segCap, N, E, NSEG);
    convert_kernel<<<(N * 64 + 255) / 256, 256, 0, stream>>>(x, hx, norm, (u32*)Zin, xf8, N);
    prep_kernel<<<1024, 256, 0, stream>>>(Wrx, Wrh, Wux, Wuh, Wcx, Wch,
                                          brx, brh, bux, buh, bcx, bch, WT, bias);
    agg_kernel<<<dim3((N + 3) / 4, 4), 256, 0, stream>>>(row_ptr, esrc, norm, xf8,
                                                         (u32*)Zin, N);
    gemm_fused_kernel<<<dim3((Mpad / 128) * 4), 256, 0, stream>>>(Zin, WT, bias, hx,
                                                                  (float*)d_out, N);
}

// Round 8
// 282.530 us; speedup vs baseline: 1.2251x; 1.2251x over previous
//
#include <hip/hip_runtime.h>
#include <hip/hip_bf16.h>

// GConvGRU (ChebConv K=2), fp32 in/out; bf16 MFMA GEMM; fp8 gather path.
// Zin row K-layout: [x | hx | px | ph] (512 bf16 = 1 KB/node).
// xf8[n]: 256 fp8 bytes = concat(x[n],hx[n]) * norm[n] (prescaled, row-major).
// 5 dispatches: memset -> bucket+prep (blockIdx-split) -> csr+convert (fused)
//   -> agg -> gemm+epilogue (fused).
// agg: round-1 verified form (8 edges/iter, dual gather, 50.8 us measured).
// GEMM: 128x128 tile, fused gate epilogue, dbuf LDS + counted vmcnt(4).

typedef unsigned short u16;
typedef unsigned int u32;
typedef __attribute__((ext_vector_type(8))) __bf16 bf16x8;
typedef __attribute__((ext_vector_type(4))) float f32x4;
typedef __attribute__((ext_vector_type(2))) float f32x2;
typedef __attribute__((ext_vector_type(4))) int int4v;

#define F_IN 128
#define HID 128
#define NPS 512           // nodes per segment (power of 2: r = d >> 9)
#define NPS_SHIFT 9

__device__ __forceinline__ u16 f2bf(float f) {
    u32 u;
    __builtin_memcpy(&u, &f, 4);
    u = (u + 0x7fffu + ((u >> 16) & 1u)) >> 16;
    return (u16)u;
}
__device__ __forceinline__ u32 packbf(float a, float b) {
    return ((u32)f2bf(b) << 16) | (u32)f2bf(a);
}
__device__ __forceinline__ float sigmoidf_(float x) {
    return 1.0f / (1.0f + __expf(-x));
}

__device__ __forceinline__ void async_copy16(void* lds, const void* gptr) {
    __builtin_amdgcn_global_load_lds(
        (__attribute__((address_space(1))) void*)gptr,
        (__attribute__((address_space(3))) void*)lds,
        16, 0, 0);
}

// ------------- 1. bucket (blocks 0..255) + weight prep (blocks 256..1279) -------------
__global__ __launch_bounds__(256) void bucket_prep_kernel(
        const int* __restrict__ src, const int* __restrict__ dst, int E,
        int* __restrict__ segCount, int2* __restrict__ bedges,
        int segCap, int edgesPerChunk, int NSEG,
        const float* __restrict__ Wrx, const float* __restrict__ Wrh,
        const float* __restrict__ Wux, const float* __restrict__ Wuh,
        const float* __restrict__ Wcx, const float* __restrict__ Wch,
        const float* __restrict__ brx, const float* __restrict__ brh,
        const float* __restrict__ bux, const float* __restrict__ buh,
        const float* __restrict__ bcx, const float* __restrict__ bch,
        u16* __restrict__ WT, float* __restrict__ bias) {
    if (blockIdx.x >= 256) {
        // ---- prep role: WT col layout c' = (f>>4)*64 + part*16 + (f&15) ----
        int t = (blockIdx.x - 256) * 256 + threadIdx.x;  // [0, 512*512)
        int cp = t >> 9, k = t & 511;
        int fc = cp >> 6, p = (cp >> 4) & 3, cf = cp & 15;
        int f = fc * 16 + cf;                 // feature 0..127
        int kpart = k >> 7;
        int kf = k & 127;
        int t01 = (kpart & 2) ? 1 : 0;
        bool isX = !(kpart & 1);
        int wi = t01 * (128 * 128) + kf * 128 + f;
        float val = 0.0f;
        if (p == 0) val = isX ? Wrx[wi] : Wrh[wi];
        else if (p == 1) val = isX ? Wux[wi] : Wuh[wi];
        else if (p == 2) { if (isX) val = Wcx[wi]; }
        else { if (!isX) val = Wch[wi]; }
        WT[t] = f2bf(val);
        if (t < 512) {
            int bp = (t >> 4) & 3;
            int bf_ = (t >> 6) * 16 + (t & 15);
            float b = 0.0f;
            if (bp == 0) b = brx[bf_] + brh[bf_];
            else if (bp == 1) b = bux[bf_] + buh[bf_];
            else if (bp == 2) b = bcx[bf_];
            else b = bch[bf_];
            bias[t] = b;
        }
        return;
    }
    // ---- bucket role ----
    __shared__ int cnt[128], base[128], pos[128];
    for (int i = threadIdx.x; i < NSEG; i += 256) cnt[i] = 0;
    __syncthreads();
    int beg = blockIdx.x * edgesPerChunk;
    int end = beg + edgesPerChunk;
    if (end > E) end = E;
    // pass 1: per-segment counts
    for (int i = beg + (int)threadIdx.x * 4; i < end; i += 256 * 4) {
        if (i + 4 <= end) {
            int4v d4 = *(const int4v*)(dst + i);
#pragma unroll
            for (int j = 0; j < 4; ++j) atomicAdd(&cnt[(unsigned)d4[j] >> NPS_SHIFT], 1);
        } else {
            for (int j = i; j < end; ++j) atomicAdd(&cnt[(unsigned)dst[j] >> NPS_SHIFT], 1);
        }
    }
    __syncthreads();
    for (int i = threadIdx.x; i < NSEG; i += 256) {
        base[i] = atomicAdd(&segCount[i], cnt[i]);
        pos[i] = 0;
    }
    __syncthreads();
    // pass 2: emit (chunk is cache-hot from pass 1)
    for (int i = beg + (int)threadIdx.x * 4; i < end; i += 256 * 4) {
        if (i + 4 <= end) {
            int4v d4 = *(const int4v*)(dst + i);
            int4v s4 = *(const int4v*)(src + i);
#pragma unroll
            for (int j = 0; j < 4; ++j) {
                int d = d4[j];
                unsigned r = (unsigned)d >> NPS_SHIFT;
                int p = atomicAdd(&pos[r], 1);
                int o = base[r] + p;
                if (o < segCap) bedges[(size_t)r * segCap + o] = make_int2(d, s4[j]);
            }
        } else {
            for (int j = i; j < end; ++j) {
                int d = dst[j];
                unsigned r = (unsigned)d >> NPS_SHIFT;
                int p = atomicAdd(&pos[r], 1);
                int o = base[r] + p;
                if (o < segCap) bedges[(size_t)r * segCap + o] = make_int2(d, src[j]);
            }
        }
    }
}

// ------------- 2. fused per-segment CSR + convert ----------------------------------
// hist + scan + row_ptr + norm + fill, then convert this segment's nodes:
// zin bf16 slots [x|hx] and prescaled fp8 rows (norm from LDS).
__global__ __launch_bounds__(1024) void csr_kernel(const int2* __restrict__ bedges,
                                                   const int* __restrict__ segCount,
                                                   int* __restrict__ row_ptr,
                                                   float* __restrict__ norm,
                                                   int* __restrict__ esrc,
                                                   const float* __restrict__ x,
                                                   const float* __restrict__ hx,
                                                   u32* __restrict__ zin,
                                                   u32* __restrict__ xf8,
                                                   int segCap, int N, int E, int NSEG) {
    __shared__ int hist[NPS];
    __shared__ int sseg[128];
    __shared__ float snorm[NPS];
    __shared__ int segBaseSh;
    int seg = blockIdx.x;
    int tid = threadIdx.x;
    int lo = seg << NPS_SHIFT;
    int npr = N - lo;
    if (npr > NPS) npr = NPS;

    // mini-scan of segCount[0..NSEG) for segBase
    if (tid < 128) sseg[tid] = (tid < NSEG) ? segCount[tid] : 0;
    __syncthreads();
    for (int off = 1; off < 128; off <<= 1) {
        int v = 0;
        if (tid < 128 && tid >= off) v = sseg[tid - off];
        __syncthreads();
        if (tid < 128) sseg[tid] += v;
        __syncthreads();
    }
    if (tid == 0) segBaseSh = (seg == 0) ? 0 : sseg[seg - 1];
    if (tid < NPS) hist[tid] = 0;
    __syncthreads();

    int cnt = segCount[seg];
    if (cnt > segCap) cnt = segCap;
    const int2* segp = bedges + (size_t)seg * segCap;

    // pass 1: histogram dst
    for (int i = tid; i < cnt; i += 1024) atomicAdd(&hist[segp[i].x - lo], 1);
    __syncthreads();
    int myCount = (tid < NPS) ? hist[tid] : 0;
    __syncthreads();
    // inclusive scan of hist
    for (int off = 1; off < NPS; off <<= 1) {
        int v = 0;
        if (tid < NPS && tid >= off) v = hist[tid - off];
        __syncthreads();
        if (tid < NPS) hist[tid] += v;
        __syncthreads();
    }
    int segBase = segBaseSh;
    if (tid < npr) {
        int excl = hist[tid] - myCount;
        row_ptr[lo + tid] = segBase + excl;
        float nv = rsqrtf((float)(myCount > 1 ? myCount : 1));
        norm[lo + tid] = nv;
        snorm[tid] = nv;
    }
    __syncthreads();
    if (tid < NPS) hist[tid] = segBase + hist[tid] - myCount;  // global cursors
    __syncthreads();
    // pass 2: fill (private window)
    for (int i = tid; i < cnt; i += 1024) {
        int2 e = segp[i];
        int slot = atomicAdd(&hist[e.x - lo], 1);
        esrc[slot] = e.y;
    }
    if (seg == NSEG - 1 && tid == 0) row_ptr[N] = E;

    // ---- convert phase: this segment's nodes (snorm already barrier-synced) ----
    for (int i = tid; i < (npr << 6); i += 1024) {
        int nl = i >> 6, c4 = i & 63;
        int n = lo + nl;
        float4 v;
        int zbase;
        if (c4 < 32) {
            v = ((const float4*)x)[n * 32 + c4];
            zbase = n * 256 + 2 * c4;
        } else {
            v = ((const float4*)hx)[n * 32 + (c4 - 32)];
            zbase = n * 256 + 64 + 2 * (c4 - 32);
        }
        zin[zbase] = packbf(v.x, v.y);
        zin[zbase + 1] = packbf(v.z, v.w);
        float ns = snorm[nl];
        u32 o = 0;
        o = (u32)__builtin_amdgcn_cvt_pk_fp8_f32(v.x * ns, v.y * ns, (int)o, false);
        o = (u32)__builtin_amdgcn_cvt_pk_fp8_f32(v.z * ns, v.w * ns, (int)o, true);
        xf8[n * 64 + c4] = o;
    }
}

// ------------- 3. wave-per-node fp8 gather-aggregate, 8 edges/iter (r1 form) --------
__global__ __launch_bounds__(256) void agg_kernel(const int* __restrict__ row_ptr,
                                                  const int* __restrict__ esrc,
                                                  const float* __restrict__ norm,
                                                  const u32* __restrict__ xf8,
                                                  u32* __restrict__ zin, int N) {
    int node = blockIdx.x * 4 + (threadIdx.x >> 6);
    int lane = threadIdx.x & 63;
    if (node >= N) return;
    int q = lane >> 4;
    int li = lane & 15;
    int beg = row_ptr[node], end = row_ptr[node + 1];
    const uint4* z4 = (const uint4*)xf8;
    f32x2 acc[8];
#pragma unroll
    for (int i = 0; i < 8; ++i) acc[i] = (f32x2){0.f, 0.f};

    int nE = end - beg;
    int mainEnd = beg + (nE & ~7);
    int e = beg;
    if (e < mainEnd) {
        int sA = esrc[e + q];
        int sB = esrc[e + q + 4];
        for (;;) {
            uint4 vA = z4[(size_t)sA * 16 + li];
            uint4 vB = z4[(size_t)sB * 16 + li];
            e += 8;
            bool more = e < mainEnd;
            int tA = 0, tB = 0;
            if (more) {
                tA = esrc[e + q];
                tB = esrc[e + q + 4];
            }
#pragma unroll
            for (int i = 0; i < 4; ++i) {
                u32 w = (i == 0) ? vA.x : (i == 1) ? vA.y : (i == 2) ? vA.z : vA.w;
                acc[2 * i] += (f32x2)__builtin_amdgcn_cvt_pk_f32_fp8((int)w, false);
                acc[2 * i + 1] += (f32x2)__builtin_amdgcn_cvt_pk_f32_fp8((int)w, true);
            }
#pragma unroll
            for (int i = 0; i < 4; ++i) {
                u32 w = (i == 0) ? vB.x : (i == 1) ? vB.y : (i == 2) ? vB.z : vB.w;
                acc[2 * i] += (f32x2)__builtin_amdgcn_cvt_pk_f32_fp8((int)w, false);
                acc[2 * i + 1] += (f32x2)__builtin_amdgcn_cvt_pk_f32_fp8((int)w, true);
            }
            if (!more) break;
            sA = tA;
            sB = tB;
        }
    }
    for (int t = mainEnd + q; t < end; t += 4) {
        int s = esrc[t];
        uint4 v = z4[(size_t)s * 16 + li];
#pragma unroll
        for (int i = 0; i < 4; ++i) {
            u32 w = (i == 0) ? v.x : (i == 1) ? v.y : (i == 2) ? v.z : v.w;
            acc[2 * i] += (f32x2)__builtin_amdgcn_cvt_pk_f32_fp8((int)w, false);
            acc[2 * i + 1] += (f32x2)__builtin_amdgcn_cvt_pk_f32_fp8((int)w, true);
        }
    }
#pragma unroll
    for (int i = 0; i < 8; ++i) {
        acc[i].x += __shfl_xor(acc[i].x, 16);
        acc[i].y += __shfl_xor(acc[i].y, 16);
        acc[i].x += __shfl_xor(acc[i].x, 32);
        acc[i].y += __shfl_xor(acc[i].y, 32);
    }
    if (lane < 16) {
        float nn = -norm[node];
        uint4 o0, o1;
        o0.x = packbf(acc[0].x * nn, acc[0].y * nn);
        o0.y = packbf(acc[1].x * nn, acc[1].y * nn);
        o0.z = packbf(acc[2].x * nn, acc[2].y * nn);
        o0.w = packbf(acc[3].x * nn, acc[3].y * nn);
        o1.x = packbf(acc[4].x * nn, acc[4].y * nn);
        o1.y = packbf(acc[5].x * nn, acc[5].y * nn);
        o1.z = packbf(acc[6].x * nn, acc[6].y * nn);
        o1.w = packbf(acc[7].x * nn, acc[7].y * nn);
        uint4* dst4 = (uint4*)zin + (size_t)node * 64 + 32 + li * 2;
        dst4[0] = o0;
        dst4[1] = o1;
    }
}

// ------------- 4. MFMA GEMM (128x128, dbuf + counted vmcnt) + fused epilogue -------------
__global__ __launch_bounds__(256) void gemm_fused_kernel(
        const u16* __restrict__ A, const u16* __restrict__ B,
        const float* __restrict__ bias, const float* __restrict__ hx,
        float* __restrict__ out, int N) {
    __shared__ __align__(16) __bf16 As[2][128 * 32];
    __shared__ __align__(16) __bf16 Bs[2][128 * 32];
    int tid = threadIdx.x;
    int wave = tid >> 6, lane = tid & 63;

    // bijective XCD swizzle (total = gridDim.x, not necessarily %8==0)
    int total = gridDim.x;
    int bid = blockIdx.x;
    int q = total >> 3, r = total & 7;
    int xcd = bid & 7, idx = bid >> 3;
    int wg = (xcd < r ? xcd * (q + 1) : r * (q + 1) + (xcd - r) * q) + idx;
    int m0 = (wg >> 2) * 128;
    int n0 = (wg & 3) * 128;

    int wm = wave & 1, wn = wave >> 1;
    int quad = lane >> 4, l15 = lane & 15;

    // per-wave staging geometry (2 chunks/wave, each 512 bf16 = 16 rows x 32)
    int chunk0 = wave * 2;
    int fl0 = chunk0 * 512 + lane * 8;
    int row0 = fl0 >> 5, col0 = fl0 & 31;
    int fl1 = (chunk0 + 1) * 512 + lane * 8;
    int row1 = fl1 >> 5, col1 = fl1 & 31;
    const u16* Arow0 = A + (size_t)(m0 + row0) * 512 + col0;
    const u16* Arow1 = A + (size_t)(m0 + row1) * 512 + col1;
    const u16* Brow0 = B + (size_t)(n0 + row0) * 512 + col0;
    const u16* Brow1 = B + (size_t)(n0 + row1) * 512 + col1;

    f32x4 acc[4][4];
#pragma unroll
    for (int mi = 0; mi < 4; ++mi)
#pragma unroll
        for (int ni = 0; ni < 4; ++ni) acc[mi][ni] = (f32x4){0.f, 0.f, 0.f, 0.f};

    // prologue: stage tile 0 into buf 0 (4 loads/wave in flight)
    async_copy16(&As[0][fl0], Arow0);
    async_copy16(&As[0][fl1], Arow1);
    async_copy16(&Bs[0][fl0], Brow0);
    async_copy16(&Bs[0][fl1], Brow1);

    int cur = 0;
    for (int t = 0; t < 16; ++t) {
        if (t < 15) {
            int k1 = (t + 1) * 32;
            async_copy16(&As[cur ^ 1][fl0], Arow0 + k1);
            async_copy16(&As[cur ^ 1][fl1], Arow1 + k1);
            async_copy16(&Bs[cur ^ 1][fl0], Brow0 + k1);
            async_copy16(&Bs[cur ^ 1][fl1], Brow1 + k1);
            // wait for tile t's 4 loads; tile t+1's 4 remain in flight
            asm volatile("s_waitcnt vmcnt(4)" ::: "memory");
        } else {
            asm volatile("s_waitcnt vmcnt(0)" ::: "memory");
        }
        __builtin_amdgcn_s_barrier();

        bf16x8 af[4], bfr[4];
#pragma unroll
        for (int mi = 0; mi < 4; ++mi)
            af[mi] = *(const bf16x8*)&As[cur][(wm * 64 + mi * 16 + l15) * 32 + quad * 8];
#pragma unroll
        for (int ni = 0; ni < 4; ++ni)
            bfr[ni] = *(const bf16x8*)&Bs[cur][(wn * 64 + ni * 16 + l15) * 32 + quad * 8];
#pragma unroll
        for (int mi = 0; mi < 4; ++mi)
#pragma unroll
            for (int ni = 0; ni < 4; ++ni)
                acc[mi][ni] = __builtin_amdgcn_mfma_f32_16x16x32_bf16(af[mi], bfr[ni],
                                                                      acc[mi][ni], 0, 0, 0);
        // this wave's ds_reads are consumed; fence the buffer swap
        asm volatile("s_waitcnt lgkmcnt(0)" ::: "memory");
        __builtin_amdgcn_s_barrier();
        cur ^= 1;
    }

    // fused epilogue: part = ni, feature f = ((n0>>6)+wn)*16 + l15
    int f = ((n0 >> 6) + wn) * 16 + l15;
    int cbase = ((n0 >> 6) + wn) * 64 + l15;
    float bR = bias[cbase + 0];
    float bU = bias[cbase + 16];
    float bX = bias[cbase + 32];
    float bH = bias[cbase + 48];
#pragma unroll
    for (int mi = 0; mi < 4; ++mi) {
        f32x4 aR = acc[mi][0];
        f32x4 aU = acc[mi][1];
        f32x4 aX = acc[mi][2];
        f32x4 aH = acc[mi][3];
#pragma unroll
        for (int r2 = 0; r2 < 4; ++r2) {
            int row = m0 + wm * 64 + mi * 16 + quad * 4 + r2;
            if (row < N) {
                float h = hx[(size_t)row * 128 + f];
                float rr = sigmoidf_(aR[r2] + bR);
                float uu = sigmoidf_(aU[r2] + bU);
                float cc = sigmoidf_((aX[r2] + bX) + (aH[r2] + bH) * rr);
                out[(size_t)row * 128 + f] = uu * h + (1.0f - uu) * cc;
            }
        }
    }
}

extern "C" void kernel_launch(void* const* d_in, const int* in_sizes, int n_in,
                              void* d_out, int out_size, void* d_ws, size_t ws_size,
                              hipStream_t stream) {
    const int* ei = (const int*)d_in[0];
    int E = in_sizes[0] / 2;
    const float* x = (const float*)d_in[1];
    const float* hx = (const float*)d_in[2];
    int N = in_sizes[1] / F_IN;
    const float* Wrx = (const float*)d_in[3];
    const float* brx = (const float*)d_in[4];
    const float* Wrh = (const float*)d_in[5];
    const float* brh = (const float*)d_in[6];
    const float* Wux = (const float*)d_in[7];
    const float* bux = (const float*)d_in[8];
    const float* Wuh = (const float*)d_in[9];
    const float* buh = (const float*)d_in[10];
    const float* Wcx = (const float*)d_in[11];
    const float* bcx = (const float*)d_in[12];
    const float* Wch = (const float*)d_in[13];
    const float* bch = (const float*)d_in[14];

    int Mpad = ((N + 127) / 128) * 128;
    int NSEG = (N + NPS - 1) / NPS;          // 98 for N=50000
    int segCap = E / NSEG + 2048;            // ~16σ slack over mean

    char* ws = (char*)d_ws;
    size_t off = 0;
    auto alloc = [&](size_t bytes) {
        size_t o = off;
        off = (off + bytes + 255) & ~(size_t)255;
        return o;
    };
    int* segCount = (int*)(ws + alloc(512));
    int* row_ptr = (int*)(ws + alloc((size_t)(N + 1) * 4));
    float* norm = (float*)(ws + alloc((size_t)N * 4));
    int* esrc = (int*)(ws + alloc((size_t)E * 4));
    int2* bedges = (int2*)(ws + alloc((size_t)NSEG * segCap * 8));
    u16* WT = (u16*)(ws + alloc((size_t)512 * 512 * 2));
    float* bias = (float*)(ws + alloc((size_t)512 * 4));
    u32* xf8 = (u32*)(ws + alloc((size_t)N * 64 * 4));
    u16* Zin = (u16*)(ws + alloc((size_t)Mpad * 512 * 2));
    (void)ws_size;

    hipMemsetAsync(segCount, 0, 512, stream);
    {
        const int bChunks = 256;
        int epc = (((E + bChunks - 1) / bChunks) + 3) & ~3;
        bucket_prep_kernel<<<bChunks + 1024, 256, 0, stream>>>(
            ei, ei + E, E, segCount, bedges, segCap, epc, NSEG,
            Wrx, Wrh, Wux, Wuh, Wcx, Wch,
            brx, brh, bux, buh, bcx, bch, WT, bias);
    }
    csr_kernel<<<NSEG, 1024, 0, stream>>>(bedges, segCount, row_ptr, norm, esrc,
                                          x, hx, (u32*)Zin, xf8,
                                          segCap, N, E, NSEG);
    agg_kernel<<<(N + 3) / 4, 256, 0, stream>>>(row_ptr, esrc, norm, xf8, (u32*)Zin, N);
    gemm_fused_kernel<<<dim3((Mpad / 128) * 4), 256, 0, stream>>>(Zin, WT, bias, hx,
                                                                  (float*)d_out, N);
}

// Round 9
// 257.269 us; speedup vs baseline: 1.3454x; 1.0982x over previous
//
#include <hip/hip_runtime.h>
#include <hip/hip_bf16.h>

// GConvGRU (ChebConv K=2), fp32 in/out; bf16 MFMA GEMM; fp8 gather path.
// Zin row K-layout: [x | hx | px | ph] (512 bf16 = 1 KB/node).
// xf8[n]: 256 fp8 bytes = concat(x[n],hx[n]) UNSCALED; agg applies norm[src]
//   per-edge via v_pk_fma (same VALU count as add; convert gains independence).
// 5 dispatches: memset -> bucket+prep+convert (blockIdx-split; convert fills
//   CUs idle during 256-block bucket) -> csr (lean) -> agg -> gemm (fused ep).
// GEMM: 128x128 tile, fused gate epilogue, dbuf LDS + counted vmcnt(4).

typedef unsigned short u16;
typedef unsigned int u32;
typedef __attribute__((ext_vector_type(8))) __bf16 bf16x8;
typedef __attribute__((ext_vector_type(4))) float f32x4;
typedef __attribute__((ext_vector_type(2))) float f32x2;
typedef __attribute__((ext_vector_type(4))) int int4v;

#define F_IN 128
#define HID 128
#define NPS 512           // nodes per segment (power of 2: r = d >> 9)
#define NPS_SHIFT 9

__device__ __forceinline__ u16 f2bf(float f) {
    u32 u;
    __builtin_memcpy(&u, &f, 4);
    u = (u + 0x7fffu + ((u >> 16) & 1u)) >> 16;
    return (u16)u;
}
__device__ __forceinline__ u32 packbf(float a, float b) {
    return ((u32)f2bf(b) << 16) | (u32)f2bf(a);
}
__device__ __forceinline__ float sigmoidf_(float x) {
    return 1.0f / (1.0f + __expf(-x));
}

__device__ __forceinline__ void async_copy16(void* lds, const void* gptr) {
    __builtin_amdgcn_global_load_lds(
        (__attribute__((address_space(1))) void*)gptr,
        (__attribute__((address_space(3))) void*)lds,
        16, 0, 0);
}

// ------------- 1. bucket [0,256) + prep [256,1280) + convert [1280,...) -------------
__global__ __launch_bounds__(256) void bucket_prep_conv_kernel(
        const int* __restrict__ src, const int* __restrict__ dst, int E,
        int* __restrict__ segCount, int2* __restrict__ bedges,
        int segCap, int edgesPerChunk, int NSEG,
        const float* __restrict__ Wrx, const float* __restrict__ Wrh,
        const float* __restrict__ Wux, const float* __restrict__ Wuh,
        const float* __restrict__ Wcx, const float* __restrict__ Wch,
        const float* __restrict__ brx, const float* __restrict__ brh,
        const float* __restrict__ bux, const float* __restrict__ buh,
        const float* __restrict__ bcx, const float* __restrict__ bch,
        u16* __restrict__ WT, float* __restrict__ bias,
        const float* __restrict__ x, const float* __restrict__ hx,
        u32* __restrict__ zin, u32* __restrict__ xf8, int N) {
    if (blockIdx.x >= 1280) {
        // ---- convert role: x,hx -> zin bf16 slots + UNSCALED fp8 rows ----
        int t = (blockIdx.x - 1280) * 256 + threadIdx.x;
        if (t >= N * 64) return;
        int n = t >> 6, c4 = t & 63;
        float4 v;
        int zbase;
        if (c4 < 32) {
            v = ((const float4*)x)[n * 32 + c4];
            zbase = n * 256 + 2 * c4;
        } else {
            v = ((const float4*)hx)[n * 32 + (c4 - 32)];
            zbase = n * 256 + 64 + 2 * (c4 - 32);
        }
        zin[zbase] = packbf(v.x, v.y);
        zin[zbase + 1] = packbf(v.z, v.w);
        u32 o = 0;
        o = (u32)__builtin_amdgcn_cvt_pk_fp8_f32(v.x, v.y, (int)o, false);
        o = (u32)__builtin_amdgcn_cvt_pk_fp8_f32(v.z, v.w, (int)o, true);
        xf8[t] = o;
        return;
    }
    if (blockIdx.x >= 256) {
        // ---- prep role: WT col layout c' = (f>>4)*64 + part*16 + (f&15) ----
        int t = (blockIdx.x - 256) * 256 + threadIdx.x;  // [0, 512*512)
        int cp = t >> 9, k = t & 511;
        int fc = cp >> 6, p = (cp >> 4) & 3, cf = cp & 15;
        int f = fc * 16 + cf;                 // feature 0..127
        int kpart = k >> 7;
        int kf = k & 127;
        int t01 = (kpart & 2) ? 1 : 0;
        bool isX = !(kpart & 1);
        int wi = t01 * (128 * 128) + kf * 128 + f;
        float val = 0.0f;
        if (p == 0) val = isX ? Wrx[wi] : Wrh[wi];
        else if (p == 1) val = isX ? Wux[wi] : Wuh[wi];
        else if (p == 2) { if (isX) val = Wcx[wi]; }
        else { if (!isX) val = Wch[wi]; }
        WT[t] = f2bf(val);
        if (t < 512) {
            int bp = (t >> 4) & 3;
            int bf_ = (t >> 6) * 16 + (t & 15);
            float b = 0.0f;
            if (bp == 0) b = brx[bf_] + brh[bf_];
            else if (bp == 1) b = bux[bf_] + buh[bf_];
            else if (bp == 2) b = bcx[bf_];
            else b = bch[bf_];
            bias[t] = b;
        }
        return;
    }
    // ---- bucket role ----
    __shared__ int cnt[128], base[128], pos[128];
    for (int i = threadIdx.x; i < NSEG; i += 256) cnt[i] = 0;
    __syncthreads();
    int beg = blockIdx.x * edgesPerChunk;
    int end = beg + edgesPerChunk;
    if (end > E) end = E;
    // pass 1: per-segment counts
    for (int i = beg + (int)threadIdx.x * 4; i < end; i += 256 * 4) {
        if (i + 4 <= end) {
            int4v d4 = *(const int4v*)(dst + i);
#pragma unroll
            for (int j = 0; j < 4; ++j) atomicAdd(&cnt[(unsigned)d4[j] >> NPS_SHIFT], 1);
        } else {
            for (int j = i; j < end; ++j) atomicAdd(&cnt[(unsigned)dst[j] >> NPS_SHIFT], 1);
        }
    }
    __syncthreads();
    for (int i = threadIdx.x; i < NSEG; i += 256) {
        base[i] = atomicAdd(&segCount[i], cnt[i]);
        pos[i] = 0;
    }
    __syncthreads();
    // pass 2: emit (chunk is cache-hot from pass 1)
    for (int i = beg + (int)threadIdx.x * 4; i < end; i += 256 * 4) {
        if (i + 4 <= end) {
            int4v d4 = *(const int4v*)(dst + i);
            int4v s4 = *(const int4v*)(src + i);
#pragma unroll
            for (int j = 0; j < 4; ++j) {
                int d = d4[j];
                unsigned r = (unsigned)d >> NPS_SHIFT;
                int p = atomicAdd(&pos[r], 1);
                int o = base[r] + p;
                if (o < segCap) bedges[(size_t)r * segCap + o] = make_int2(d, s4[j]);
            }
        } else {
            for (int j = i; j < end; ++j) {
                int d = dst[j];
                unsigned r = (unsigned)d >> NPS_SHIFT;
                int p = atomicAdd(&pos[r], 1);
                int o = base[r] + p;
                if (o < segCap) bedges[(size_t)r * segCap + o] = make_int2(d, src[j]);
            }
        }
    }
}

// ------------- 2. per-segment CSR (lean): hist + scan + row_ptr + norm + fill -------
__global__ __launch_bounds__(1024) void csr_kernel(const int2* __restrict__ bedges,
                                                   const int* __restrict__ segCount,
                                                   int* __restrict__ row_ptr,
                                                   float* __restrict__ norm,
                                                   int* __restrict__ esrc,
                                                   int segCap, int N, int E, int NSEG) {
    __shared__ int hist[NPS];
    __shared__ int sseg[128];
    __shared__ int segBaseSh;
    int seg = blockIdx.x;
    int tid = threadIdx.x;
    int lo = seg << NPS_SHIFT;
    int npr = N - lo;
    if (npr > NPS) npr = NPS;

    // mini-scan of segCount[0..NSEG) for segBase
    if (tid < 128) sseg[tid] = (tid < NSEG) ? segCount[tid] : 0;
    __syncthreads();
    for (int off = 1; off < 128; off <<= 1) {
        int v = 0;
        if (tid < 128 && tid >= off) v = sseg[tid - off];
        __syncthreads();
        if (tid < 128) sseg[tid] += v;
        __syncthreads();
    }
    if (tid == 0) segBaseSh = (seg == 0) ? 0 : sseg[seg - 1];
    if (tid < NPS) hist[tid] = 0;
    __syncthreads();

    int cnt = segCount[seg];
    if (cnt > segCap) cnt = segCap;
    const int2* segp = bedges + (size_t)seg * segCap;

    // pass 1: histogram dst
    for (int i = tid; i < cnt; i += 1024) atomicAdd(&hist[segp[i].x - lo], 1);
    __syncthreads();
    int myCount = (tid < NPS) ? hist[tid] : 0;
    __syncthreads();
    // inclusive scan of hist
    for (int off = 1; off < NPS; off <<= 1) {
        int v = 0;
        if (tid < NPS && tid >= off) v = hist[tid - off];
        __syncthreads();
        if (tid < NPS) hist[tid] += v;
        __syncthreads();
    }
    int segBase = segBaseSh;
    if (tid < npr) {
        int excl = hist[tid] - myCount;
        row_ptr[lo + tid] = segBase + excl;
        norm[lo + tid] = rsqrtf((float)(myCount > 1 ? myCount : 1));
    }
    __syncthreads();
    if (tid < NPS) hist[tid] = segBase + hist[tid] - myCount;  // global cursors
    __syncthreads();
    // pass 2: fill (private window)
    for (int i = tid; i < cnt; i += 1024) {
        int2 e = segp[i];
        int slot = atomicAdd(&hist[e.x - lo], 1);
        esrc[slot] = e.y;
    }
    if (seg == NSEG - 1 && tid == 0) row_ptr[N] = E;
}

// ------------- 3. agg: wave-per-node, 8 edges/iter, per-edge norm[src] FMA ----------
__device__ __forceinline__ void accum4s(f32x2* acc, uint4 v, float ns) {
#pragma unroll
    for (int i = 0; i < 4; ++i) {
        u32 w = (i == 0) ? v.x : (i == 1) ? v.y : (i == 2) ? v.z : v.w;
        f32x2 lo = (f32x2)__builtin_amdgcn_cvt_pk_f32_fp8((int)w, false);
        f32x2 hi = (f32x2)__builtin_amdgcn_cvt_pk_f32_fp8((int)w, true);
        acc[2 * i] += lo * ns;
        acc[2 * i + 1] += hi * ns;
    }
}

__global__ __launch_bounds__(256) void agg_kernel(const int* __restrict__ row_ptr,
                                                  const int* __restrict__ esrc,
                                                  const float* __restrict__ norm,
                                                  const u32* __restrict__ xf8,
                                                  u32* __restrict__ zin, int N) {
    int node = blockIdx.x * 4 + (threadIdx.x >> 6);
    int lane = threadIdx.x & 63;
    if (node >= N) return;
    int q = lane >> 4;
    int li = lane & 15;
    int beg = row_ptr[node], end = row_ptr[node + 1];
    const uint4* z4 = (const uint4*)xf8;
    f32x2 acc[8];
#pragma unroll
    for (int i = 0; i < 8; ++i) acc[i] = (f32x2){0.f, 0.f};

    int nE = end - beg;
    int mainEnd = beg + (nE & ~7);
    int e = beg;
    if (e < mainEnd) {
        int sA = esrc[e + q];
        int sB = esrc[e + q + 4];
        float nsA = norm[sA];
        float nsB = norm[sB];
        for (;;) {
            uint4 vA = z4[(size_t)sA * 16 + li];
            uint4 vB = z4[(size_t)sB * 16 + li];
            e += 8;
            bool more = e < mainEnd;
            int tA = 0, tB = 0;
            float ntA = 0.f, ntB = 0.f;
            if (more) {
                tA = esrc[e + q];
                tB = esrc[e + q + 4];
                ntA = norm[tA];
                ntB = norm[tB];
            }
            accum4s(acc, vA, nsA);
            accum4s(acc, vB, nsB);
            if (!more) break;
            sA = tA;
            sB = tB;
            nsA = ntA;
            nsB = ntB;
        }
    }
    for (int t = mainEnd + q; t < end; t += 4) {
        int s = esrc[t];
        float ns = norm[s];
        uint4 v = z4[(size_t)s * 16 + li];
        accum4s(acc, v, ns);
    }
#pragma unroll
    for (int i = 0; i < 8; ++i) {
        acc[i].x += __shfl_xor(acc[i].x, 16);
        acc[i].y += __shfl_xor(acc[i].y, 16);
        acc[i].x += __shfl_xor(acc[i].x, 32);
        acc[i].y += __shfl_xor(acc[i].y, 32);
    }
    if (lane < 16) {
        float nn = -norm[node];
        uint4 o0, o1;
        o0.x = packbf(acc[0].x * nn, acc[0].y * nn);
        o0.y = packbf(acc[1].x * nn, acc[1].y * nn);
        o0.z = packbf(acc[2].x * nn, acc[2].y * nn);
        o0.w = packbf(acc[3].x * nn, acc[3].y * nn);
        o1.x = packbf(acc[4].x * nn, acc[4].y * nn);
        o1.y = packbf(acc[5].x * nn, acc[5].y * nn);
        o1.z = packbf(acc[6].x * nn, acc[6].y * nn);
        o1.w = packbf(acc[7].x * nn, acc[7].y * nn);
        uint4* dst4 = (uint4*)zin + (size_t)node * 64 + 32 + li * 2;
        dst4[0] = o0;
        dst4[1] = o1;
    }
}

// ------------- 4. MFMA GEMM (128x128, dbuf + counted vmcnt) + fused epilogue -------------
__global__ __launch_bounds__(256) void gemm_fused_kernel(
        const u16* __restrict__ A, const u16* __restrict__ B,
        const float* __restrict__ bias, const float* __restrict__ hx,
        float* __restrict__ out, int N) {
    __shared__ __align__(16) __bf16 As[2][128 * 32];
    __shared__ __align__(16) __bf16 Bs[2][128 * 32];
    int tid = threadIdx.x;
    int wave = tid >> 6, lane = tid & 63;

    // bijective XCD swizzle (total = gridDim.x, not necessarily %8==0)
    int total = gridDim.x;
    int bid = blockIdx.x;
    int q = total >> 3, r = total & 7;
    int xcd = bid & 7, idx = bid >> 3;
    int wg = (xcd < r ? xcd * (q + 1) : r * (q + 1) + (xcd - r) * q) + idx;
    int m0 = (wg >> 2) * 128;
    int n0 = (wg & 3) * 128;

    int wm = wave & 1, wn = wave >> 1;
    int quad = lane >> 4, l15 = lane & 15;

    // per-wave staging geometry (2 chunks/wave, each 512 bf16 = 16 rows x 32)
    int chunk0 = wave * 2;
    int fl0 = chunk0 * 512 + lane * 8;
    int row0 = fl0 >> 5, col0 = fl0 & 31;
    int fl1 = (chunk0 + 1) * 512 + lane * 8;
    int row1 = fl1 >> 5, col1 = fl1 & 31;
    const u16* Arow0 = A + (size_t)(m0 + row0) * 512 + col0;
    const u16* Arow1 = A + (size_t)(m0 + row1) * 512 + col1;
    const u16* Brow0 = B + (size_t)(n0 + row0) * 512 + col0;
    const u16* Brow1 = B + (size_t)(n0 + row1) * 512 + col1;

    f32x4 acc[4][4];
#pragma unroll
    for (int mi = 0; mi < 4; ++mi)
#pragma unroll
        for (int ni = 0; ni < 4; ++ni) acc[mi][ni] = (f32x4){0.f, 0.f, 0.f, 0.f};

    // prologue: stage tile 0 into buf 0 (4 loads/wave in flight)
    async_copy16(&As[0][fl0], Arow0);
    async_copy16(&As[0][fl1], Arow1);
    async_copy16(&Bs[0][fl0], Brow0);
    async_copy16(&Bs[0][fl1], Brow1);

    int cur = 0;
    for (int t = 0; t < 16; ++t) {
        if (t < 15) {
            int k1 = (t + 1) * 32;
            async_copy16(&As[cur ^ 1][fl0], Arow0 + k1);
            async_copy16(&As[cur ^ 1][fl1], Arow1 + k1);
            async_copy16(&Bs[cur ^ 1][fl0], Brow0 + k1);
            async_copy16(&Bs[cur ^ 1][fl1], Brow1 + k1);
            // wait for tile t's 4 loads; tile t+1's 4 remain in flight
            asm volatile("s_waitcnt vmcnt(4)" ::: "memory");
        } else {
            asm volatile("s_waitcnt vmcnt(0)" ::: "memory");
        }
        __builtin_amdgcn_s_barrier();

        bf16x8 af[4], bfr[4];
#pragma unroll
        for (int mi = 0; mi < 4; ++mi)
            af[mi] = *(const bf16x8*)&As[cur][(wm * 64 + mi * 16 + l15) * 32 + quad * 8];
#pragma unroll
        for (int ni = 0; ni < 4; ++ni)
            bfr[ni] = *(const bf16x8*)&Bs[cur][(wn * 64 + ni * 16 + l15) * 32 + quad * 8];
#pragma unroll
        for (int mi = 0; mi < 4; ++mi)
#pragma unroll
            for (int ni = 0; ni < 4; ++ni)
                acc[mi][ni] = __builtin_amdgcn_mfma_f32_16x16x32_bf16(af[mi], bfr[ni],
                                                                      acc[mi][ni], 0, 0, 0);
        // this wave's ds_reads are consumed; fence the buffer swap
        asm volatile("s_waitcnt lgkmcnt(0)" ::: "memory");
        __builtin_amdgcn_s_barrier();
        cur ^= 1;
    }

    // fused epilogue: part = ni, feature f = ((n0>>6)+wn)*16 + l15
    int f = ((n0 >> 6) + wn) * 16 + l15;
    int cbase = ((n0 >> 6) + wn) * 64 + l15;
    float bR = bias[cbase + 0];
    float bU = bias[cbase + 16];
    float bX = bias[cbase + 32];
    float bH = bias[cbase + 48];
#pragma unroll
    for (int mi = 0; mi < 4; ++mi) {
        f32x4 aR = acc[mi][0];
        f32x4 aU = acc[mi][1];
        f32x4 aX = acc[mi][2];
        f32x4 aH = acc[mi][3];
#pragma unroll
        for (int r2 = 0; r2 < 4; ++r2) {
            int row = m0 + wm * 64 + mi * 16 + quad * 4 + r2;
            if (row < N) {
                float h = hx[(size_t)row * 128 + f];
                float rr = sigmoidf_(aR[r2] + bR);
                float uu = sigmoidf_(aU[r2] + bU);
                float cc = sigmoidf_((aX[r2] + bX) + (aH[r2] + bH) * rr);
                out[(size_t)row * 128 + f] = uu * h + (1.0f - uu) * cc;
            }
        }
    }
}

extern "C" void kernel_launch(void* const* d_in, const int* in_sizes, int n_in,
                              void* d_out, int out_size, void* d_ws, size_t ws_size,
                              hipStream_t stream) {
    const int* ei = (const int*)d_in[0];
    int E = in_sizes[0] / 2;
    const float* x = (const float*)d_in[1];
    const float* hx = (const float*)d_in[2];
    int N = in_sizes[1] / F_IN;
    const float* Wrx = (const float*)d_in[3];
    const float* brx = (const float*)d_in[4];
    const float* Wrh = (const float*)d_in[5];
    const float* brh = (const float*)d_in[6];
    const float* Wux = (const float*)d_in[7];
    const float* bux = (const float*)d_in[8];
    const float* Wuh = (const float*)d_in[9];
    const float* buh = (const float*)d_in[10];
    const float* Wcx = (const float*)d_in[11];
    const float* bcx = (const float*)d_in[12];
    const float* Wch = (const float*)d_in[13];
    const float* bch = (const float*)d_in[14];

    int Mpad = ((N + 127) / 128) * 128;
    int NSEG = (N + NPS - 1) / NPS;          // 98 for N=50000
    int segCap = E / NSEG + 2048;            // ~16σ slack over mean

    char* ws = (char*)d_ws;
    size_t off = 0;
    auto alloc = [&](size_t bytes) {
        size_t o = off;
        off = (off + bytes + 255) & ~(size_t)255;
        return o;
    };
    int* segCount = (int*)(ws + alloc(512));
    int* row_ptr = (int*)(ws + alloc((size_t)(N + 1) * 4));
    float* norm = (float*)(ws + alloc((size_t)N * 4));
    int* esrc = (int*)(ws + alloc((size_t)E * 4));
    int2* bedges = (int2*)(ws + alloc((size_t)NSEG * segCap * 8));
    u16* WT = (u16*)(ws + alloc((size_t)512 * 512 * 2));
    float* bias = (float*)(ws + alloc((size_t)512 * 4));
    u32* xf8 = (u32*)(ws + alloc((size_t)N * 64 * 4));
    u16* Zin = (u16*)(ws + alloc((size_t)Mpad * 512 * 2));
    (void)ws_size;

    hipMemsetAsync(segCount, 0, 512, stream);
    {
        const int bChunks = 256;
        int epc = (((E + bChunks - 1) / bChunks) + 3) & ~3;
        int convBlocks = (N * 64 + 255) / 256;
        bucket_prep_conv_kernel<<<1280 + convBlocks, 256, 0, stream>>>(
            ei, ei + E, E, segCount, bedges, segCap, epc, NSEG,
            Wrx, Wrh, Wux, Wuh, Wcx, Wch,
            brx, brh, bux, buh, bcx, bch, WT, bias,
            x, hx, (u32*)Zin, xf8, N);
    }
    csr_kernel<<<NSEG, 1024, 0, stream>>>(bedges, segCount, row_ptr, norm, esrc,
                                          segCap, N, E, NSEG);
    agg_kernel<<<(N + 3) / 4, 256, 0, stream>>>(row_ptr, esrc, norm, xf8, (u32*)Zin, N);
    gemm_fused_kernel<<<dim3((Mpad / 128) * 4), 256, 0, stream>>>(Zin, WT, bias, hx,
                                                                  (float*)d_out, N);
}

// Round 10
// 251.528 us; speedup vs baseline: 1.3761x; 1.0228x over previous
//
#include <hip/hip_runtime.h>
#include <hip/hip_bf16.h>

// GConvGRU (ChebConv K=2), fp32 in/out; bf16 MFMA GEMM; fp8 gather path.
// Zin row K-layout: [x | hx | px | ph] (512 bf16 = 1 KB/node).
// xf8[n]: 256 fp8 bytes = concat(x[n],hx[n]) UNSCALED; agg applies norm[src]
//   per-edge via pk_fma, with indices prefetched 2 iters ahead and norms 1
//   ahead so the dependent norm gather hides under a full accum iteration.
// 5 dispatches: memset -> bucket+prep+convert (blockIdx-split) -> csr (lean,
//   NPS=256 -> 196 blocks) -> agg -> gemm (fused epilogue).
// GEMM: 128x128 tile, fused gate epilogue, dbuf LDS + counted vmcnt(4).

typedef unsigned short u16;
typedef unsigned int u32;
typedef __attribute__((ext_vector_type(8))) __bf16 bf16x8;
typedef __attribute__((ext_vector_type(4))) float f32x4;
typedef __attribute__((ext_vector_type(2))) float f32x2;
typedef __attribute__((ext_vector_type(4))) int int4v;

#define F_IN 128
#define HID 128
#define NPS 256           // nodes per segment (power of 2: r = d >> 8)
#define NPS_SHIFT 8
#define MAXSEG 256        // array sizing (NSEG = 196 for N=50000)

__device__ __forceinline__ u16 f2bf(float f) {
    u32 u;
    __builtin_memcpy(&u, &f, 4);
    u = (u + 0x7fffu + ((u >> 16) & 1u)) >> 16;
    return (u16)u;
}
__device__ __forceinline__ u32 packbf(float a, float b) {
    return ((u32)f2bf(b) << 16) | (u32)f2bf(a);
}
__device__ __forceinline__ float sigmoidf_(float x) {
    return 1.0f / (1.0f + __expf(-x));
}

__device__ __forceinline__ void async_copy16(void* lds, const void* gptr) {
    __builtin_amdgcn_global_load_lds(
        (__attribute__((address_space(1))) void*)gptr,
        (__attribute__((address_space(3))) void*)lds,
        16, 0, 0);
}

// ------------- 1. bucket [0,256) + prep [256,1280) + convert [1280,...) -------------
__global__ __launch_bounds__(256) void bucket_prep_conv_kernel(
        const int* __restrict__ src, const int* __restrict__ dst, int E,
        int* __restrict__ segCount, int2* __restrict__ bedges,
        int segCap, int edgesPerChunk, int NSEG,
        const float* __restrict__ Wrx, const float* __restrict__ Wrh,
        const float* __restrict__ Wux, const float* __restrict__ Wuh,
        const float* __restrict__ Wcx, const float* __restrict__ Wch,
        const float* __restrict__ brx, const float* __restrict__ brh,
        const float* __restrict__ bux, const float* __restrict__ buh,
        const float* __restrict__ bcx, const float* __restrict__ bch,
        u16* __restrict__ WT, float* __restrict__ bias,
        const float* __restrict__ x, const float* __restrict__ hx,
        u32* __restrict__ zin, u32* __restrict__ xf8, int N) {
    if (blockIdx.x >= 1280) {
        // ---- convert role: x,hx -> zin bf16 slots + UNSCALED fp8 rows ----
        int t = (blockIdx.x - 1280) * 256 + threadIdx.x;
        if (t >= N * 64) return;
        int n = t >> 6, c4 = t & 63;
        float4 v;
        int zbase;
        if (c4 < 32) {
            v = ((const float4*)x)[n * 32 + c4];
            zbase = n * 256 + 2 * c4;
        } else {
            v = ((const float4*)hx)[n * 32 + (c4 - 32)];
            zbase = n * 256 + 64 + 2 * (c4 - 32);
        }
        zin[zbase] = packbf(v.x, v.y);
        zin[zbase + 1] = packbf(v.z, v.w);
        u32 o = 0;
        o = (u32)__builtin_amdgcn_cvt_pk_fp8_f32(v.x, v.y, (int)o, false);
        o = (u32)__builtin_amdgcn_cvt_pk_fp8_f32(v.z, v.w, (int)o, true);
        xf8[t] = o;
        return;
    }
    if (blockIdx.x >= 256) {
        // ---- prep role: WT col layout c' = (f>>4)*64 + part*16 + (f&15) ----
        int t = (blockIdx.x - 256) * 256 + threadIdx.x;  // [0, 512*512)
        int cp = t >> 9, k = t & 511;
        int fc = cp >> 6, p = (cp >> 4) & 3, cf = cp & 15;
        int f = fc * 16 + cf;                 // feature 0..127
        int kpart = k >> 7;
        int kf = k & 127;
        int t01 = (kpart & 2) ? 1 : 0;
        bool isX = !(kpart & 1);
        int wi = t01 * (128 * 128) + kf * 128 + f;
        float val = 0.0f;
        if (p == 0) val = isX ? Wrx[wi] : Wrh[wi];
        else if (p == 1) val = isX ? Wux[wi] : Wuh[wi];
        else if (p == 2) { if (isX) val = Wcx[wi]; }
        else { if (!isX) val = Wch[wi]; }
        WT[t] = f2bf(val);
        if (t < 512) {
            int bp = (t >> 4) & 3;
            int bf_ = (t >> 6) * 16 + (t & 15);
            float b = 0.0f;
            if (bp == 0) b = brx[bf_] + brh[bf_];
            else if (bp == 1) b = bux[bf_] + buh[bf_];
            else if (bp == 2) b = bcx[bf_];
            else b = bch[bf_];
            bias[t] = b;
        }
        return;
    }
    // ---- bucket role ----
    __shared__ int cnt[MAXSEG], base[MAXSEG], pos[MAXSEG];
    for (int i = threadIdx.x; i < NSEG; i += 256) cnt[i] = 0;
    __syncthreads();
    int beg = blockIdx.x * edgesPerChunk;
    int end = beg + edgesPerChunk;
    if (end > E) end = E;
    // pass 1: per-segment counts
    for (int i = beg + (int)threadIdx.x * 4; i < end; i += 256 * 4) {
        if (i + 4 <= end) {
            int4v d4 = *(const int4v*)(dst + i);
#pragma unroll
            for (int j = 0; j < 4; ++j) atomicAdd(&cnt[(unsigned)d4[j] >> NPS_SHIFT], 1);
        } else {
            for (int j = i; j < end; ++j) atomicAdd(&cnt[(unsigned)dst[j] >> NPS_SHIFT], 1);
        }
    }
    __syncthreads();
    for (int i = threadIdx.x; i < NSEG; i += 256) {
        base[i] = atomicAdd(&segCount[i], cnt[i]);
        pos[i] = 0;
    }
    __syncthreads();
    // pass 2: emit (chunk is cache-hot from pass 1)
    for (int i = beg + (int)threadIdx.x * 4; i < end; i += 256 * 4) {
        if (i + 4 <= end) {
            int4v d4 = *(const int4v*)(dst + i);
            int4v s4 = *(const int4v*)(src + i);
#pragma unroll
            for (int j = 0; j < 4; ++j) {
                int d = d4[j];
                unsigned r = (unsigned)d >> NPS_SHIFT;
                int p = atomicAdd(&pos[r], 1);
                int o = base[r] + p;
                if (o < segCap) bedges[(size_t)r * segCap + o] = make_int2(d, s4[j]);
            }
        } else {
            for (int j = i; j < end; ++j) {
                int d = dst[j];
                unsigned r = (unsigned)d >> NPS_SHIFT;
                int p = atomicAdd(&pos[r], 1);
                int o = base[r] + p;
                if (o < segCap) bedges[(size_t)r * segCap + o] = make_int2(d, src[j]);
            }
        }
    }
}

// ------------- 2. per-segment CSR (lean, NPS=256): hist+scan+row_ptr+norm+fill ------
__global__ __launch_bounds__(1024) void csr_kernel(const int2* __restrict__ bedges,
                                                   const int* __restrict__ segCount,
                                                   int* __restrict__ row_ptr,
                                                   float* __restrict__ norm,
                                                   int* __restrict__ esrc,
                                                   int segCap, int N, int E, int NSEG) {
    __shared__ int hist[NPS];
    __shared__ int sseg[MAXSEG];
    __shared__ int segBaseSh;
    int seg = blockIdx.x;
    int tid = threadIdx.x;
    int lo = seg << NPS_SHIFT;
    int npr = N - lo;
    if (npr > NPS) npr = NPS;

    // mini-scan of segCount[0..NSEG) for segBase
    if (tid < MAXSEG) sseg[tid] = (tid < NSEG) ? segCount[tid] : 0;
    __syncthreads();
    for (int off = 1; off < MAXSEG; off <<= 1) {
        int v = 0;
        if (tid < MAXSEG && tid >= off) v = sseg[tid - off];
        __syncthreads();
        if (tid < MAXSEG) sseg[tid] += v;
        __syncthreads();
    }
    if (tid == 0) segBaseSh = (seg == 0) ? 0 : sseg[seg - 1];
    if (tid < NPS) hist[tid] = 0;
    __syncthreads();

    int cnt = segCount[seg];
    if (cnt > segCap) cnt = segCap;
    const int2* segp = bedges + (size_t)seg * segCap;

    // pass 1: histogram dst
    for (int i = tid; i < cnt; i += 1024) atomicAdd(&hist[segp[i].x - lo], 1);
    __syncthreads();
    int myCount = (tid < NPS) ? hist[tid] : 0;
    __syncthreads();
    // inclusive scan of hist
    for (int off = 1; off < NPS; off <<= 1) {
        int v = 0;
        if (tid < NPS && tid >= off) v = hist[tid - off];
        __syncthreads();
        if (tid < NPS) hist[tid] += v;
        __syncthreads();
    }
    int segBase = segBaseSh;
    if (tid < npr) {
        int excl = hist[tid] - myCount;
        row_ptr[lo + tid] = segBase + excl;
        norm[lo + tid] = rsqrtf((float)(myCount > 1 ? myCount : 1));
    }
    __syncthreads();
    if (tid < NPS) hist[tid] = segBase + hist[tid] - myCount;  // global cursors
    __syncthreads();
    // pass 2: fill (private window)
    for (int i = tid; i < cnt; i += 1024) {
        int2 e = segp[i];
        int slot = atomicAdd(&hist[e.x - lo], 1);
        esrc[slot] = e.y;
    }
    if (seg == NSEG - 1 && tid == 0) row_ptr[N] = E;
}

// ------------- 3. agg: wave-per-node, 8 edges/iter, idx 2-ahead / norm 1-ahead ------
__device__ __forceinline__ void accum4s(f32x2* acc, uint4 v, float ns) {
#pragma unroll
    for (int i = 0; i < 4; ++i) {
        u32 w = (i == 0) ? v.x : (i == 1) ? v.y : (i == 2) ? v.z : v.w;
        f32x2 lo = (f32x2)__builtin_amdgcn_cvt_pk_f32_fp8((int)w, false);
        f32x2 hi = (f32x2)__builtin_amdgcn_cvt_pk_f32_fp8((int)w, true);
        acc[2 * i] += lo * ns;
        acc[2 * i + 1] += hi * ns;
    }
}

__global__ __launch_bounds__(256) void agg_kernel(const int* __restrict__ row_ptr,
                                                  const int* __restrict__ esrc,
                                                  const float* __restrict__ norm,
                                                  const u32* __restrict__ xf8,
                                                  u32* __restrict__ zin, int N) {
    int node = blockIdx.x * 4 + (threadIdx.x >> 6);
    int lane = threadIdx.x & 63;
    if (node >= N) return;
    int q = lane >> 4;
    int li = lane & 15;
    int beg = row_ptr[node], end = row_ptr[node + 1];
    const uint4* z4 = (const uint4*)xf8;
    f32x2 acc[8];
#pragma unroll
    for (int i = 0; i < 8; ++i) acc[i] = (f32x2){0.f, 0.f};

    int nE = end - beg;
    int T = (nE & ~7) >> 3;   // main 8-edge iterations
    int e = beg;
    if (T > 0) {
        // prologue: idx(0), norm(0); idx(1) if present
        int s0A = esrc[e + q], s0B = esrc[e + q + 4];
        float n0A = norm[s0A], n0B = norm[s0B];
        int s1A = 0, s1B = 0;
        if (T > 1) {
            s1A = esrc[e + 8 + q];
            s1B = esrc[e + 12 + q];
        }
        for (int t = 0; t < T; ++t) {
            uint4 vA = z4[(size_t)s0A * 16 + li];
            uint4 vB = z4[(size_t)s0B * 16 + li];
            // idx(t+2) and norm(t+1) issued a full iteration before use
            int s2A = 0, s2B = 0;
            if (t + 2 < T) {
                s2A = esrc[e + 16 + q];
                s2B = esrc[e + 20 + q];
            }
            float n1A = 0.f, n1B = 0.f;
            if (t + 1 < T) {
                n1A = norm[s1A];
                n1B = norm[s1B];
            }
            accum4s(acc, vA, n0A);
            accum4s(acc, vB, n0B);
            s0A = s1A; s0B = s1B;
            n0A = n1A; n0B = n1B;
            s1A = s2A; s1B = s2B;
            e += 8;
        }
    }
    for (int t2 = beg + T * 8 + q; t2 < end; t2 += 4) {
        int s = esrc[t2];
        float ns = norm[s];
        uint4 v = z4[(size_t)s * 16 + li];
        accum4s(acc, v, ns);
    }
#pragma unroll
    for (int i = 0; i < 8; ++i) {
        acc[i].x += __shfl_xor(acc[i].x, 16);
        acc[i].y += __shfl_xor(acc[i].y, 16);
        acc[i].x += __shfl_xor(acc[i].x, 32);
        acc[i].y += __shfl_xor(acc[i].y, 32);
    }
    if (lane < 16) {
        float nn = -norm[node];
        uint4 o0, o1;
        o0.x = packbf(acc[0].x * nn, acc[0].y * nn);
        o0.y = packbf(acc[1].x * nn, acc[1].y * nn);
        o0.z = packbf(acc[2].x * nn, acc[2].y * nn);
        o0.w = packbf(acc[3].x * nn, acc[3].y * nn);
        o1.x = packbf(acc[4].x * nn, acc[4].y * nn);
        o1.y = packbf(acc[5].x * nn, acc[5].y * nn);
        o1.z = packbf(acc[6].x * nn, acc[6].y * nn);
        o1.w = packbf(acc[7].x * nn, acc[7].y * nn);
        uint4* dst4 = (uint4*)zin + (size_t)node * 64 + 32 + li * 2;
        dst4[0] = o0;
        dst4[1] = o1;
    }
}

// ------------- 4. MFMA GEMM (128x128, dbuf + counted vmcnt) + fused epilogue -------------
__global__ __launch_bounds__(256) void gemm_fused_kernel(
        const u16* __restrict__ A, const u16* __restrict__ B,
        const float* __restrict__ bias, const float* __restrict__ hx,
        float* __restrict__ out, int N) {
    __shared__ __align__(16) __bf16 As[2][128 * 32];
    __shared__ __align__(16) __bf16 Bs[2][128 * 32];
    int tid = threadIdx.x;
    int wave = tid >> 6, lane = tid & 63;

    // bijective XCD swizzle (total = gridDim.x, not necessarily %8==0)
    int total = gridDim.x;
    int bid = blockIdx.x;
    int q = total >> 3, r = total & 7;
    int xcd = bid & 7, idx = bid >> 3;
    int wg = (xcd < r ? xcd * (q + 1) : r * (q + 1) + (xcd - r) * q) + idx;
    int m0 = (wg >> 2) * 128;
    int n0 = (wg & 3) * 128;

    int wm = wave & 1, wn = wave >> 1;
    int quad = lane >> 4, l15 = lane & 15;

    // per-wave staging geometry (2 chunks/wave, each 512 bf16 = 16 rows x 32)
    int chunk0 = wave * 2;
    int fl0 = chunk0 * 512 + lane * 8;
    int row0 = fl0 >> 5, col0 = fl0 & 31;
    int fl1 = (chunk0 + 1) * 512 + lane * 8;
    int row1 = fl1 >> 5, col1 = fl1 & 31;
    const u16* Arow0 = A + (size_t)(m0 + row0) * 512 + col0;
    const u16* Arow1 = A + (size_t)(m0 + row1) * 512 + col1;
    const u16* Brow0 = B + (size_t)(n0 + row0) * 512 + col0;
    const u16* Brow1 = B + (size_t)(n0 + row1) * 512 + col1;

    f32x4 acc[4][4];
#pragma unroll
    for (int mi = 0; mi < 4; ++mi)
#pragma unroll
        for (int ni = 0; ni < 4; ++ni) acc[mi][ni] = (f32x4){0.f, 0.f, 0.f, 0.f};

    // prologue: stage tile 0 into buf 0 (4 loads/wave in flight)
    async_copy16(&As[0][fl0], Arow0);
    async_copy16(&As[0][fl1], Arow1);
    async_copy16(&Bs[0][fl0], Brow0);
    async_copy16(&Bs[0][fl1], Brow1);

    int cur = 0;
    for (int t = 0; t < 16; ++t) {
        if (t < 15) {
            int k1 = (t + 1) * 32;
            async_copy16(&As[cur ^ 1][fl0], Arow0 + k1);
            async_copy16(&As[cur ^ 1][fl1], Arow1 + k1);
            async_copy16(&Bs[cur ^ 1][fl0], Brow0 + k1);
            async_copy16(&Bs[cur ^ 1][fl1], Brow1 + k1);
            // wait for tile t's 4 loads; tile t+1's 4 remain in flight
            asm volatile("s_waitcnt vmcnt(4)" ::: "memory");
        } else {
            asm volatile("s_waitcnt vmcnt(0)" ::: "memory");
        }
        __builtin_amdgcn_s_barrier();

        bf16x8 af[4], bfr[4];
#pragma unroll
        for (int mi = 0; mi < 4; ++mi)
            af[mi] = *(const bf16x8*)&As[cur][(wm * 64 + mi * 16 + l15) * 32 + quad * 8];
#pragma unroll
        for (int ni = 0; ni < 4; ++ni)
            bfr[ni] = *(const bf16x8*)&Bs[cur][(wn * 64 + ni * 16 + l15) * 32 + quad * 8];
#pragma unroll
        for (int mi = 0; mi < 4; ++mi)
#pragma unroll
            for (int ni = 0; ni < 4; ++ni)
                acc[mi][ni] = __builtin_amdgcn_mfma_f32_16x16x32_bf16(af[mi], bfr[ni],
                                                                      acc[mi][ni], 0, 0, 0);
        // this wave's ds_reads are consumed; fence the buffer swap
        asm volatile("s_waitcnt lgkmcnt(0)" ::: "memory");
        __builtin_amdgcn_s_barrier();
        cur ^= 1;
    }

    // fused epilogue: part = ni, feature f = ((n0>>6)+wn)*16 + l15
    int f = ((n0 >> 6) + wn) * 16 + l15;
    int cbase = ((n0 >> 6) + wn) * 64 + l15;
    float bR = bias[cbase + 0];
    float bU = bias[cbase + 16];
    float bX = bias[cbase + 32];
    float bH = bias[cbase + 48];
#pragma unroll
    for (int mi = 0; mi < 4; ++mi) {
        f32x4 aR = acc[mi][0];
        f32x4 aU = acc[mi][1];
        f32x4 aX = acc[mi][2];
        f32x4 aH = acc[mi][3];
#pragma unroll
        for (int r2 = 0; r2 < 4; ++r2) {
            int row = m0 + wm * 64 + mi * 16 + quad * 4 + r2;
            if (row < N) {
                float h = hx[(size_t)row * 128 + f];
                float rr = sigmoidf_(aR[r2] + bR);
                float uu = sigmoidf_(aU[r2] + bU);
                float cc = sigmoidf_((aX[r2] + bX) + (aH[r2] + bH) * rr);
                out[(size_t)row * 128 + f] = uu * h + (1.0f - uu) * cc;
            }
        }
    }
}

extern "C" void kernel_launch(void* const* d_in, const int* in_sizes, int n_in,
                              void* d_out, int out_size, void* d_ws, size_t ws_size,
                              hipStream_t stream) {
    const int* ei = (const int*)d_in[0];
    int E = in_sizes[0] / 2;
    const float* x = (const float*)d_in[1];
    const float* hx = (const float*)d_in[2];
    int N = in_sizes[1] / F_IN;
    const float* Wrx = (const float*)d_in[3];
    const float* brx = (const float*)d_in[4];
    const float* Wrh = (const float*)d_in[5];
    const float* brh = (const float*)d_in[6];
    const float* Wux = (const float*)d_in[7];
    const float* bux = (const float*)d_in[8];
    const float* Wuh = (const float*)d_in[9];
    const float* buh = (const float*)d_in[10];
    const float* Wcx = (const float*)d_in[11];
    const float* bcx = (const float*)d_in[12];
    const float* Wch = (const float*)d_in[13];
    const float* bch = (const float*)d_in[14];

    int Mpad = ((N + 127) / 128) * 128;
    int NSEG = (N + NPS - 1) / NPS;          // 196 for N=50000
    int segCap = E / NSEG + 2048;            // ~22σ slack over mean

    char* ws = (char*)d_ws;
    size_t off = 0;
    auto alloc = [&](size_t bytes) {
        size_t o = off;
        off = (off + bytes + 255) & ~(size_t)255;
        return o;
    };
    int* segCount = (int*)(ws + alloc(1024));
    int* row_ptr = (int*)(ws + alloc((size_t)(N + 1) * 4));
    float* norm = (float*)(ws + alloc((size_t)N * 4));
    int* esrc = (int*)(ws + alloc((size_t)E * 4));
    int2* bedges = (int2*)(ws + alloc((size_t)NSEG * segCap * 8));
    u16* WT = (u16*)(ws + alloc((size_t)512 * 512 * 2));
    float* bias = (float*)(ws + alloc((size_t)512 * 4));
    u32* xf8 = (u32*)(ws + alloc((size_t)N * 64 * 4));
    u16* Zin = (u16*)(ws + alloc((size_t)Mpad * 512 * 2));
    (void)ws_size;

    hipMemsetAsync(segCount, 0, 1024, stream);
    {
        const int bChunks = 256;
        int epc = (((E + bChunks - 1) / bChunks) + 3) & ~3;
        int convBlocks = (N * 64 + 255) / 256;
        bucket_prep_conv_kernel<<<1280 + convBlocks, 256, 0, stream>>>(
            ei, ei + E, E, segCount, bedges, segCap, epc, NSEG,
            Wrx, Wrh, Wux, Wuh, Wcx, Wch,
            brx, brh, bux, buh, bcx, bch, WT, bias,
            x, hx, (u32*)Zin, xf8, N);
    }
    csr_kernel<<<NSEG, 1024, 0, stream>>>(bedges, segCount, row_ptr, norm, esrc,
                                          segCap, N, E, NSEG);
    agg_kernel<<<(N + 3) / 4, 256, 0, stream>>>(row_ptr, esrc, norm, xf8, (u32*)Zin, N);
    gemm_fused_kernel<<<dim3((Mpad / 128) * 4), 256, 0, stream>>>(Zin, WT, bias, hx,
                                                                  (float*)d_out, N);
}